// Round 1
// baseline (192.324 us; speedup 1.0000x reference)
//
#include <hip/hip_runtime.h>

// RecursiveNN root = sum of leaf embeddings: out[b,d] = sum_l emb[ids[b,l], d]
// B=4096 trees, L=64 leaves, D=300, VOCAB=100000, fp32.

#define NB 4096
#define NL 64
#define ND 300
#define ND4 75   // float4 per row (300 floats * 4B = 1200 B = 75 * 16 B)

__global__ __launch_bounds__(256, 4) void recnn_root_sum(
    const int* __restrict__ word_ids,     // [NB, NL]
    const float4* __restrict__ emb4,      // [VOCAB, ND4]
    float* __restrict__ out)              // [NB, ND]
{
    __shared__ int ids[NL];
    __shared__ float partial[4][ND];

    const int b    = blockIdx.x;
    const int tid  = threadIdx.x;
    const int wave = tid >> 6;
    const int lane = tid & 63;

    if (tid < NL) ids[tid] = word_ids[b * NL + tid];
    __syncthreads();

    float4 acc0 = make_float4(0.f, 0.f, 0.f, 0.f);
    float4 acc1 = make_float4(0.f, 0.f, 0.f, 0.f);

    // Each wave handles 16 leaves.
    const int l0 = wave * 16;
    #pragma unroll
    for (int i = 0; i < 16; ++i) {
        const int row = ids[l0 + i];
        const float4* rp = emb4 + (size_t)row * ND4;
        float4 v0 = rp[lane];                 // cols 0..63 (coalesced 1024 B)
        acc0.x += v0.x; acc0.y += v0.y; acc0.z += v0.z; acc0.w += v0.w;
        if (lane < ND4 - 64) {                // cols 64..74 (lanes 0..10)
            float4 v1 = rp[64 + lane];
            acc1.x += v1.x; acc1.y += v1.y; acc1.z += v1.z; acc1.w += v1.w;
        }
    }

    // Store per-wave partials to LDS (contiguous float4 per lane: conflict-free).
    *reinterpret_cast<float4*>(&partial[wave][lane * 4]) = acc0;
    if (lane < ND4 - 64)
        *reinterpret_cast<float4*>(&partial[wave][256 + lane * 4]) = acc1;
    __syncthreads();

    // Cross-wave reduce + store (300 floats, coalesced).
    for (int t = tid; t < ND; t += 256) {
        out[(size_t)b * ND + t] =
            partial[0][t] + partial[1][t] + partial[2][t] + partial[3][t];
    }
}

extern "C" void kernel_launch(void* const* d_in, const int* in_sizes, int n_in,
                              void* d_out, int out_size, void* d_ws, size_t ws_size,
                              hipStream_t stream) {
    const int*    word_ids = (const int*)d_in[0];      // [4096, 64] int32
    const float4* emb4     = (const float4*)d_in[1];   // [100000, 300] f32 as float4
    float*        out      = (float*)d_out;            // [4096, 300] f32

    recnn_root_sum<<<NB, 256, 0, stream>>>(word_ids, emb4, out);
}